// Round 3
// baseline (1063.440 us; speedup 1.0000x reference)
//
#include <hip/hip_runtime.h>
#include <stdint.h>

typedef _Float16 half8 __attribute__((ext_vector_type(8)));   // 8 fp16 = 16 B
typedef float    f32x4 __attribute__((ext_vector_type(4)));

#define BM 128
#define BN 128
#define BK 32
#define BLSTRIDE 40   // B-tile row stride in halves (32 data + 8 pad = 80 B)

// C = A(MxK) @ B(KxN), both row-major. B is always fp32 (exact fp16 values).
// A is fp32 (stage 1) or fp16 (stage 2, the act scratch). fp32 accum.
// OUT_IS_F32: round to fp16 (mirrors reference astype) then store fp32 (final
// output buffer) vs store fp16 (act scratch).
// 128x128 tile, 4 waves x (64x64), mfma_f32_16x16x32_f16, 4x4 acc per wave.
template<int K, int N, bool A_IS_F16, bool OUT_IS_F32>
__global__ __launch_bounds__(256)
void gemm_nn(const void* __restrict__ Av, const float* __restrict__ B,
             void* __restrict__ Cv)
{
    __shared__ __align__(16) _Float16 As[BM * BK];        // 8 KB, [m][k]
    __shared__ __align__(16) _Float16 Bl[BN * BLSTRIDE];  // 10 KB, [n][k] padded

    const int tid  = threadIdx.x;
    const int lane = tid & 63;
    const int wave = tid >> 6;

    const int bm0 = blockIdx.x * BM;   // x = m: 16 m-blocks share one B n-panel
    const int bn0 = blockIdx.y * BN;

    const int m_off = (wave >> 1) * 64;
    const int n_off = (wave & 1) * 64;

    const int lm = lane & 15;          // index within 16 (mfma row/col)
    const int lk = lane >> 4;          // mfma k-group (0..3)

    f32x4 acc[4][4];
    #pragma unroll
    for (int i = 0; i < 4; ++i)
        #pragma unroll
        for (int j = 0; j < 4; ++j)
            acc[i][j] = (f32x4)0.0f;

    // A staging: thread t -> rows (t>>2), (t>>2)+64, k-chunk (t&3)*8
    const int arow = tid >> 2;
    const int acol = (tid & 3) * 8;
    // B staging: thread t -> column n = t&127, k-half kh = t>>7 (16 k's each)
    const int bn_local = tid & 127;
    const int kh       = tid >> 7;

    const float*    Af32 = (const float*)Av;
    const _Float16* Af16 = (const _Float16*)Av;
    const float*    Bp   = B + (size_t)(kh * 16) * N + bn0 + bn_local;

    for (int kt = 0; kt < K / BK; ++kt) {
        const int k0 = kt * BK;

        // ---- load A chunks (global), convert to fp16 ----
        half8 a0, a1;
        if (A_IS_F16) {
            a0 = *(const half8*)(Af16 + (size_t)(bm0 + arow)      * K + k0 + acol);
            a1 = *(const half8*)(Af16 + (size_t)(bm0 + arow + 64) * K + k0 + acol);
        } else {
            const float* r0 = Af32 + (size_t)(bm0 + arow)      * K + k0 + acol;
            const float* r1 = Af32 + (size_t)(bm0 + arow + 64) * K + k0 + acol;
            float4 x0 = *(const float4*)r0, x1 = *(const float4*)(r0 + 4);
            float4 y0 = *(const float4*)r1, y1 = *(const float4*)(r1 + 4);
            a0[0]=(_Float16)x0.x; a0[1]=(_Float16)x0.y; a0[2]=(_Float16)x0.z; a0[3]=(_Float16)x0.w;
            a0[4]=(_Float16)x1.x; a0[5]=(_Float16)x1.y; a0[6]=(_Float16)x1.z; a0[7]=(_Float16)x1.w;
            a1[0]=(_Float16)y0.x; a1[1]=(_Float16)y0.y; a1[2]=(_Float16)y0.z; a1[3]=(_Float16)y0.w;
            a1[4]=(_Float16)y1.x; a1[5]=(_Float16)y1.y; a1[6]=(_Float16)y1.z; a1[7]=(_Float16)y1.w;
        }

        // ---- load B column slice (k-major, coalesced along n), convert ----
        const float* p = Bp + (size_t)k0 * N;
        half8 w0, w1;
        #pragma unroll
        for (int i = 0; i < 8; ++i) w0[i] = (_Float16)p[(size_t)i * N];
        #pragma unroll
        for (int i = 0; i < 8; ++i) w1[i] = (_Float16)p[(size_t)(8 + i) * N];

        // ---- LDS writes ----
        *(half8*)&As[arow * BK + acol]        = a0;
        *(half8*)&As[(arow + 64) * BK + acol] = a1;
        *(half8*)&Bl[bn_local * BLSTRIDE + kh * 16]     = w0;
        *(half8*)&Bl[bn_local * BLSTRIDE + kh * 16 + 8] = w1;

        __syncthreads();

        // ---- compute: 8x ds_read_b128 + 16x mfma per wave ----
        half8 af[4], bfr[4];
        #pragma unroll
        for (int mi = 0; mi < 4; ++mi)
            af[mi] = *(const half8*)&As[(m_off + mi * 16 + lm) * BK + lk * 8];
        #pragma unroll
        for (int ni = 0; ni < 4; ++ni)
            bfr[ni] = *(const half8*)&Bl[(n_off + ni * 16 + lm) * BLSTRIDE + lk * 8];

        #pragma unroll
        for (int mi = 0; mi < 4; ++mi)
            #pragma unroll
            for (int ni = 0; ni < 4; ++ni)
                acc[mi][ni] = __builtin_amdgcn_mfma_f32_16x16x32_f16(
                    af[mi], bfr[ni], acc[mi][ni], 0, 0, 0);

        __syncthreads();
    }

    // ---- epilogue: C/D layout col=lane&15, row=(lane>>4)*4+reg ----
    #pragma unroll
    for (int mi = 0; mi < 4; ++mi) {
        #pragma unroll
        for (int ni = 0; ni < 4; ++ni) {
            #pragma unroll
            for (int r = 0; r < 4; ++r) {
                const int row = bm0 + m_off + mi * 16 + lk * 4 + r;
                const int col = bn0 + n_off + ni * 16 + lm;
                const _Float16 h = (_Float16)acc[mi][ni][r];  // mirror astype(fp16)
                if (OUT_IS_F32) ((float*)Cv)[(size_t)row * N + col] = (float)h;
                else            ((_Float16*)Cv)[(size_t)row * N + col] = h;
            }
        }
    }
}

extern "C" void kernel_launch(void* const* d_in, const int* in_sizes, int n_in,
                              void* d_out, int out_size, void* d_ws, size_t ws_size,
                              hipStream_t stream) {
    // Reference dtype is float16 -> harness materializes as FP32 on device.
    //   d_in[0] = A_prev (2048x4096) fp32, d_in[1] = W_prev (4096x4096) fp32,
    //   d_in[2] = W_up (4096x16384) fp32. d_out = 2048x16384 fp32.
    const float* A  = (const float*)d_in[0];
    const float* Wp = (const float*)d_in[1];
    const float* Wu = (const float*)d_in[2];

    void* act = d_ws;               // 2048x4096 fp16 = 16 MB scratch
    // act = fp16(A @ W_prev)   (M=2048, K=4096, N=4096)
    gemm_nn<4096, 4096, false, false>
        <<<dim3(2048 / BM, 4096 / BN), 256, 0, stream>>>(A, Wp, act);
    // out = fp32(fp16(act @ W_up))   (M=2048, K=4096, N=16384)
    gemm_nn<4096, 16384, true, true>
        <<<dim3(2048 / BM, 16384 / BN), 256, 0, stream>>>(act, Wu, d_out);
}

// Round 4
// 911.740 us; speedup vs baseline: 1.1664x; 1.1664x over previous
//
#include <hip/hip_runtime.h>
#include <stdint.h>

typedef _Float16 half8 __attribute__((ext_vector_type(8)));   // 8 fp16 = 16 B
typedef float    f32x4 __attribute__((ext_vector_type(4)));

#define BM 128
#define BN 128
#define BK 32
#define BLSTRIDE 40   // fallback path: B-tile row stride in halves

// ---------------------------------------------------------------------------
// Prepass kernels
// ---------------------------------------------------------------------------

// fp32 -> fp16 elementwise (values are exact fp16, conversion lossless).
__global__ __launch_bounds__(256)
void cvt_f32_f16(const float* __restrict__ in, _Float16* __restrict__ out, size_t n4)
{
    size_t i = (size_t)blockIdx.x * 256 + threadIdx.x;
    if (i >= n4) return;
    float4 v = ((const float4*)in)[i];
    _Float16 h4[4] = {(_Float16)v.x, (_Float16)v.y, (_Float16)v.z, (_Float16)v.w};
    *(uint2*)&out[i * 4] = *(uint2*)h4;
}

// fp32 [K][N] row-major  ->  fp16 [N][K] row-major (transpose + convert).
// 64x64 tiles via LDS (65-half padded rows -> conflict-free).
__global__ __launch_bounds__(256)
void transpose_cvt(const float* __restrict__ in, _Float16* __restrict__ out,
                   int Kdim, int Ndim)
{
    __shared__ _Float16 t[64][65];
    const int n0 = blockIdx.x * 64, k0 = blockIdx.y * 64;
    const int tx = threadIdx.x & 63, ty = threadIdx.x >> 6;
    #pragma unroll
    for (int i = 0; i < 16; ++i) {
        const int kk = ty + 4 * i;
        t[kk][tx] = (_Float16)in[(size_t)(k0 + kk) * Ndim + n0 + tx];
    }
    __syncthreads();
    #pragma unroll
    for (int i = 0; i < 16; ++i) {
        const int nn = ty + 4 * i;
        out[(size_t)(n0 + nn) * Kdim + k0 + tx] = t[tx][nn];
    }
}

// ---------------------------------------------------------------------------
// Fast path: m97-structure GEMM. A [M][K] fp16, Bt [N][K] fp16 (pre-transposed).
// 128x128 tile, BK=32, 4 waves x (64x64), mfma_f32_16x16x32_f16, 4x4 acc/wave.
// Both tiles staged via global_load_lds width 16 (lane-linear LDS, no pad).
// ---------------------------------------------------------------------------
template<int K, int N, bool OUT_IS_F32>
__global__ __launch_bounds__(256)
void gemm_tt(const _Float16* __restrict__ A, const _Float16* __restrict__ Bt,
             void* __restrict__ Cv)
{
    __shared__ __align__(16) _Float16 As[BM * BK];   // 8 KB [m][k]
    __shared__ __align__(16) _Float16 Bs[BN * BK];   // 8 KB [n][k]

    const int tid  = threadIdx.x;
    const int lane = tid & 63;
    const int wave = tid >> 6;

    const int bm0 = blockIdx.x * BM;   // x = m: m-blocks sharing a B n-panel run adjacently
    const int bn0 = blockIdx.y * BN;

    const int m_off = (wave >> 1) * 64;
    const int n_off = (wave & 1) * 64;

    const int lm = lane & 15;
    const int lk = lane >> 4;

    f32x4 acc[4][4];
    #pragma unroll
    for (int i = 0; i < 4; ++i)
        #pragma unroll
        for (int j = 0; j < 4; ++j)
            acc[i][j] = (f32x4)0.0f;

    const int row = tid >> 2;            // staging row (0..63 per issue half)
    const int col = (tid & 3) * 8;       // k-chunk in halves

    for (int kt = 0; kt < K / BK; ++kt) {
        const int k0 = kt * BK;

        // --- stage A and B: 2 issues x 256 lanes x 16 B each ---
        #pragma unroll
        for (int issue = 0; issue < 2; ++issue) {
            const int c = issue * 256 + tid;           // 16-B chunk index
            const int r = c >> 2;
            const int cc = (c & 3) * 8;
            __builtin_amdgcn_global_load_lds(
                (const __attribute__((address_space(1))) uint32_t*)
                    (A + (size_t)(bm0 + r) * K + k0 + cc),
                (__attribute__((address_space(3))) uint32_t*)&As[c * 8],
                16, 0, 0);
            __builtin_amdgcn_global_load_lds(
                (const __attribute__((address_space(1))) uint32_t*)
                    (Bt + (size_t)(bn0 + r) * K + k0 + cc),
                (__attribute__((address_space(3))) uint32_t*)&Bs[c * 8],
                16, 0, 0);
        }

        __syncthreads();

        // --- compute: 8x ds_read_b128 + 16x mfma per wave ---
        half8 af[4], bfr[4];
        #pragma unroll
        for (int mi = 0; mi < 4; ++mi)
            af[mi] = *(const half8*)&As[(m_off + mi * 16 + lm) * BK + lk * 8];
        #pragma unroll
        for (int ni = 0; ni < 4; ++ni)
            bfr[ni] = *(const half8*)&Bs[(n_off + ni * 16 + lm) * BK + lk * 8];

        #pragma unroll
        for (int mi = 0; mi < 4; ++mi)
            #pragma unroll
            for (int ni = 0; ni < 4; ++ni)
                acc[mi][ni] = __builtin_amdgcn_mfma_f32_16x16x32_f16(
                    af[mi], bfr[ni], acc[mi][ni], 0, 0, 0);

        __syncthreads();
    }

    // --- epilogue: C/D layout col=lane&15, row=(lane>>4)*4+reg ---
    #pragma unroll
    for (int mi = 0; mi < 4; ++mi) {
        #pragma unroll
        for (int ni = 0; ni < 4; ++ni) {
            #pragma unroll
            for (int r = 0; r < 4; ++r) {
                const int orow = bm0 + m_off + mi * 16 + lk * 4 + r;
                const int ocol = bn0 + n_off + ni * 16 + lm;
                const _Float16 h = (_Float16)acc[mi][ni][r];   // mirror astype(fp16)
                if (OUT_IS_F32) ((float*)Cv)[(size_t)orow * N + ocol] = (float)h;
                else            ((_Float16*)Cv)[(size_t)orow * N + ocol] = h;
            }
        }
    }
}

// ---------------------------------------------------------------------------
// Fallback path (round-3, passing): NN GEMM with in-kernel transpose staging.
// ---------------------------------------------------------------------------
template<int K, int N, bool A_IS_F16, bool OUT_IS_F32>
__global__ __launch_bounds__(256)
void gemm_nn(const void* __restrict__ Av, const float* __restrict__ B,
             void* __restrict__ Cv)
{
    __shared__ __align__(16) _Float16 As[BM * BK];
    __shared__ __align__(16) _Float16 Bl[BN * BLSTRIDE];

    const int tid  = threadIdx.x;
    const int lane = tid & 63;
    const int wave = tid >> 6;
    const int bm0 = blockIdx.x * BM;
    const int bn0 = blockIdx.y * BN;
    const int m_off = (wave >> 1) * 64;
    const int n_off = (wave & 1) * 64;
    const int lm = lane & 15;
    const int lk = lane >> 4;

    f32x4 acc[4][4];
    #pragma unroll
    for (int i = 0; i < 4; ++i)
        #pragma unroll
        for (int j = 0; j < 4; ++j)
            acc[i][j] = (f32x4)0.0f;

    const int arow = tid >> 2;
    const int acol = (tid & 3) * 8;
    const int bn_local = tid & 127;
    const int kh       = tid >> 7;

    const float*    Af32 = (const float*)Av;
    const _Float16* Af16 = (const _Float16*)Av;
    const float*    Bp   = B + (size_t)(kh * 16) * N + bn0 + bn_local;

    for (int kt = 0; kt < K / BK; ++kt) {
        const int k0 = kt * BK;
        half8 a0, a1;
        if (A_IS_F16) {
            a0 = *(const half8*)(Af16 + (size_t)(bm0 + arow)      * K + k0 + acol);
            a1 = *(const half8*)(Af16 + (size_t)(bm0 + arow + 64) * K + k0 + acol);
        } else {
            const float* r0 = Af32 + (size_t)(bm0 + arow)      * K + k0 + acol;
            const float* r1 = Af32 + (size_t)(bm0 + arow + 64) * K + k0 + acol;
            float4 x0 = *(const float4*)r0, x1 = *(const float4*)(r0 + 4);
            float4 y0 = *(const float4*)r1, y1 = *(const float4*)(r1 + 4);
            a0[0]=(_Float16)x0.x; a0[1]=(_Float16)x0.y; a0[2]=(_Float16)x0.z; a0[3]=(_Float16)x0.w;
            a0[4]=(_Float16)x1.x; a0[5]=(_Float16)x1.y; a0[6]=(_Float16)x1.z; a0[7]=(_Float16)x1.w;
            a1[0]=(_Float16)y0.x; a1[1]=(_Float16)y0.y; a1[2]=(_Float16)y0.z; a1[3]=(_Float16)y0.w;
            a1[4]=(_Float16)y1.x; a1[5]=(_Float16)y1.y; a1[6]=(_Float16)y1.z; a1[7]=(_Float16)y1.w;
        }
        const float* p = Bp + (size_t)k0 * N;
        half8 w0, w1;
        #pragma unroll
        for (int i = 0; i < 8; ++i) w0[i] = (_Float16)p[(size_t)i * N];
        #pragma unroll
        for (int i = 0; i < 8; ++i) w1[i] = (_Float16)p[(size_t)(8 + i) * N];

        *(half8*)&As[arow * BK + acol]        = a0;
        *(half8*)&As[(arow + 64) * BK + acol] = a1;
        *(half8*)&Bl[bn_local * BLSTRIDE + kh * 16]     = w0;
        *(half8*)&Bl[bn_local * BLSTRIDE + kh * 16 + 8] = w1;

        __syncthreads();

        half8 af[4], bfr[4];
        #pragma unroll
        for (int mi = 0; mi < 4; ++mi)
            af[mi] = *(const half8*)&As[(m_off + mi * 16 + lm) * BK + lk * 8];
        #pragma unroll
        for (int ni = 0; ni < 4; ++ni)
            bfr[ni] = *(const half8*)&Bl[(n_off + ni * 16 + lm) * BLSTRIDE + lk * 8];

        #pragma unroll
        for (int mi = 0; mi < 4; ++mi)
            #pragma unroll
            for (int ni = 0; ni < 4; ++ni)
                acc[mi][ni] = __builtin_amdgcn_mfma_f32_16x16x32_f16(
                    af[mi], bfr[ni], acc[mi][ni], 0, 0, 0);

        __syncthreads();
    }

    #pragma unroll
    for (int mi = 0; mi < 4; ++mi) {
        #pragma unroll
        for (int ni = 0; ni < 4; ++ni) {
            #pragma unroll
            for (int r = 0; r < 4; ++r) {
                const int orow = bm0 + m_off + mi * 16 + lk * 4 + r;
                const int ocol = bn0 + n_off + ni * 16 + lm;
                const _Float16 h = (_Float16)acc[mi][ni][r];
                if (OUT_IS_F32) ((float*)Cv)[(size_t)orow * N + ocol] = (float)h;
                else            ((_Float16*)Cv)[(size_t)orow * N + ocol] = h;
            }
        }
    }
}

extern "C" void kernel_launch(void* const* d_in, const int* in_sizes, int n_in,
                              void* d_out, int out_size, void* d_ws, size_t ws_size,
                              hipStream_t stream) {
    // fp16-valued fp32 inputs: A_prev (2048x4096), W_prev (4096x4096),
    // W_up (4096x16384). Output: 2048x16384 fp32 (fp16-rounded values).
    const float* A  = (const float*)d_in[0];
    const float* Wp = (const float*)d_in[1];
    const float* Wu = (const float*)d_in[2];

    const size_t MB = 1024 * 1024;
    const size_t need = 192 * MB;   // A16(16) + Wpt(32) + Wut(128) + act(16)

    if (ws_size >= need) {
        _Float16* A16 = (_Float16*)((char*)d_ws);
        _Float16* Wpt = (_Float16*)((char*)d_ws + 16 * MB);
        _Float16* Wut = (_Float16*)((char*)d_ws + 48 * MB);
        _Float16* act = (_Float16*)((char*)d_ws + 176 * MB);

        // Prepass: convert A, transpose+convert both weights.
        cvt_f32_f16<<<(2048 * 4096 / 4 + 255) / 256, 256, 0, stream>>>(A, A16, 2048 * 4096 / 4);
        transpose_cvt<<<dim3(4096 / 64, 4096 / 64), 256, 0, stream>>>(Wp, Wpt, 4096, 4096);
        transpose_cvt<<<dim3(16384 / 64, 4096 / 64), 256, 0, stream>>>(Wu, Wut, 4096, 16384);

        // act = fp16(A @ W_prev)
        gemm_tt<4096, 4096, false>
            <<<dim3(2048 / BM, 4096 / BN), 256, 0, stream>>>(A16, Wpt, act);
        // out = fp32(fp16(act @ W_up))
        gemm_tt<4096, 16384, true>
            <<<dim3(2048 / BM, 16384 / BN), 256, 0, stream>>>(act, Wut, d_out);
    } else {
        // Fallback: round-3 passing path (act fp16 in ws).
        void* act = d_ws;
        gemm_nn<4096, 4096, false, false>
            <<<dim3(2048 / BM, 4096 / BN), 256, 0, stream>>>(A, Wp, act);
        gemm_nn<4096, 16384, true, true>
            <<<dim3(2048 / BM, 16384 / BN), 256, 0, stream>>>(act, Wu, d_out);
    }
}